// Round 16
// baseline (409.674 us; speedup 1.0000x reference)
//
#include <hip/hip_runtime.h>

#define DMODEL 768
#define NHEADS 12
#define MAXFULL 16
#define NSTEP 24   // DMODEL / 32 (gemmWo)

typedef __attribute__((ext_vector_type(8))) short short8;
typedef __attribute__((ext_vector_type(4))) float f32x4;
typedef __attribute__((ext_vector_type(8))) unsigned short u16x8;

__device__ __forceinline__ unsigned pack2_bf16(float a, float b) {
  unsigned ua = __float_as_uint(a), ub = __float_as_uint(b);
  ua = (ua + 0x7fffu + ((ua >> 16) & 1u)) >> 16;
  ub = (ub + 0x7fffu + ((ub >> 16) & 1u)) & 0xffff0000u;
  return ua | ub;
}
__device__ __forceinline__ unsigned short bf16_1(float a) {
  unsigned ua = __float_as_uint(a);
  return (unsigned short)((ua + 0x7fffu + ((ua >> 16) & 1u)) >> 16);
}
__device__ __forceinline__ float b2f(unsigned short u) {
  return __uint_as_float(((unsigned)u) << 16);
}
__device__ __forceinline__ float4 lo4(u16x8 u) {
  return make_float4(b2f(u[0]), b2f(u[1]), b2f(u[2]), b2f(u[3]));
}
__device__ __forceinline__ float4 hi4(u16x8 u) {
  return make_float4(b2f(u[4]), b2f(u[5]), b2f(u[6]), b2f(u[7]));
}

// direct global->LDS DMA, 16 B per lane; LDS dest = wave-uniform base + lane*16
__device__ __forceinline__ void load16_lds(const void* g, void* l) {
  __builtin_amdgcn_global_load_lds(
      (const __attribute__((address_space(1))) unsigned int*)g,
      (__attribute__((address_space(3))) unsigned int*)l, 16, 0, 0);
}

// W f32->bf16 conversion (blocks 0..nb-1) + segment build (last block).
// x conversion is now fused into gemm256's A staging (reg-stage + pack).
__global__ __launch_bounds__(256) void convAll(const float* __restrict__ w0,
    const float* __restrict__ w1, const float* __restrict__ w2,
    const float* __restrict__ w3, unsigned* __restrict__ o0,
    unsigned* __restrict__ o1, unsigned* __restrict__ o2,
    unsigned* __restrict__ o3, int wcount,
    const int* __restrict__ qm, const int* __restrict__ ids,
    const int* __restrict__ padp, int n, int f, int* __restrict__ left,
    int* __restrict__ right, int* __restrict__ nvalid,
    int* __restrict__ fullrank, int* __restrict__ fullist,
    int* __restrict__ nfull) {
  __shared__ int cnt[256];
  const int t = threadIdx.x;
  if (blockIdx.x == gridDim.x - 1) {
    // ---- segment build (one block, 256 threads) ----
    const int per = (n + 255) >> 8;
    const int base = t * per;
    int c = 0;
    for (int i = 0; i < per; ++i) {
      int p = base + i;
      if (p < n && qm[p] != 0) ++c;
    }
    cnt[t] = c;
    __syncthreads();
    for (int off = 1; off < 256; off <<= 1) {
      int v = (t >= off) ? cnt[t - off] : 0;
      __syncthreads();
      cnt[t] += v;
      __syncthreads();
    }
    int r = cnt[t] - c;  // exclusive prefix
    for (int i = 0; i < per; ++i) {
      int p = base + i;
      if (p < n && qm[p] != 0) {
        if (r < f) left[r] = p;
        ++r;
      }
    }
    __syncthreads();
    const int pad = *padp;
    for (int i = t; i < f; i += 256) {
      int L0 = left[i];
      int R0 = (i + 1 < f) ? left[i + 1] : n;
      right[i] = R0;
      int cv = 0;
      for (int p = L0; p < R0; ++p) cv += (ids[p] != pad) ? 1 : 0;
      nvalid[i] = cv;
      fullrank[i] = -1;
    }
    __syncthreads();
    // order-preserving parallel compaction of {i : nvalid[i]==0}
    const int perf = (f + 255) >> 8;
    const int zbase = t * perf;
    int zc = 0;
    for (int i = 0; i < perf; ++i) {
      int idx = zbase + i;
      if (idx < f && nvalid[idx] == 0) ++zc;
    }
    cnt[t] = zc;
    __syncthreads();
    for (int off = 1; off < 256; off <<= 1) {
      int v = (t >= off) ? cnt[t - off] : 0;
      __syncthreads();
      cnt[t] += v;
      __syncthreads();
    }
    int zr = cnt[t] - zc;  // exclusive prefix (feature-ordered)
    for (int i = 0; i < perf; ++i) {
      int idx = zbase + i;
      if (idx < f && nvalid[idx] == 0) {
        if (zr < MAXFULL) { fullist[zr] = idx; fullrank[idx] = zr; }
        ++zr;
      }
    }
    __syncthreads();
    if (t == 0) *nfull = (cnt[255] < MAXFULL) ? cnt[255] : MAXFULL;
    return;
  }
  // ---- W conversion (grid-stride over nb blocks) ----
  const int nb = gridDim.x - 1;
  const int nvw = wcount >> 2;
  const float* src[4] = {w0, w1, w2, w3};
  unsigned* dst[4] = {o0, o1, o2, o3};
  for (int idx = blockIdx.x * 256 + t; idx < 4 * nvw; idx += nb * 256) {
    int m = idx / nvw, r = idx - m * nvw;
    float4 v = ((const float4*)src[m])[r];
    dst[m][2 * r]     = pack2_bf16(v.x, v.y);
    dst[m][2 * r + 1] = pack2_bf16(v.z, v.w);
  }
}

struct GSeg {
  const float* A;            // f32 activations [*,768] (converted in-kernel)
  const unsigned short* W;   // bf16 weights [col][k]
  const float* bias;
  const int* row_map;        // optional row gather
  void* C;                   // f32 out (obf=0) or bf16 out (obf=1)
  int base;                  // first flat block id of this segment
  int nwg;                   // blocks in this segment
  int obf;                   // 1 -> write bf16
};

typedef unsigned short LdsTile[2][256][32];  // [k-panel][row][32 elems=64B]

// ---------------- 256x256 main GEMM ----------------------------------------
// A is f32: reg-staged (global f32 -> pack bf16 -> ds_write into the same
// linear slots the DMA used); B (weights) stays global_load_lds. Per K-tile
// issue group G(t) = [4 B-DMA, 8 A-loads] = 12 vmem ops; 2 groups in flight;
// steady wait vmcnt(12) = G(t) complete (oldest-first semantics). Then
// pack+ds_write A(t), lgkmcnt(0), barrier, compute, barrier, issue G(t+2).
__global__ __launch_bounds__(512, 2) void gemm256(GSeg g0, GSeg g1, GSeg g2) {
  __shared__ __attribute__((aligned(16))) LdsTile As[2];
  __shared__ __attribute__((aligned(16))) LdsTile Bs[2];
  const int t = threadIdx.x;
  const int id = blockIdx.x;
  const GSeg& d = (id >= g2.base) ? g2 : ((id >= g1.base) ? g1 : g0);
  const int lid = id - d.base;
  // bijective XCD swizzle when nwg % 8 == 0 (K/V segments: 96 -> cpx=12)
  const int j = (d.nwg & 7) == 0 ? (lid & 7) * (d.nwg >> 3) + (lid >> 3) : lid;
  const int bn = (j % 3) * 256;
  const int bm = (j / 3) * 256;
  const int lane = t & 63, wid = t >> 6;
  const int m16 = lane & 15, quad = lane >> 4;
  const int qx = quad ^ ((m16 >> 1) & 3);   // T2 reader involution (64B rows)
  const int wr = wid >> 2, wc = wid & 3;    // 2x4 wave grid

  f32x4 acc[8][4];
#pragma unroll
  for (int i = 0; i < 8; ++i)
#pragma unroll
    for (int j2 = 0; j2 < 4; ++j2) acc[i][j2] = (f32x4){0.f, 0.f, 0.f, 0.f};

  const int srow = wid * 16 + (lane >> 2);                    // 0..127
  const int skc = ((lane & 3) ^ ((lane >> 3) & 3)) * 8;       // T2 source perm
  int arow0, arow1;
  if (d.row_map) {
    arow0 = d.row_map[bm + srow];
    arow1 = d.row_map[bm + 128 + srow];
  } else {
    arow0 = bm + srow;
    arow1 = bm + 128 + srow;
  }
  const int wrow0 = bn + srow, wrow1 = bn + 128 + srow;
  const int woff0 = (wid * 16) * 32;          // elems (ushort)
  const int woff1 = (128 + wid * 16) * 32;
  const int wd0 = (woff0 >> 1) + lane * 4;    // dwords incl lane slot
  const int wd1 = (woff1 >> 1) + lane * 4;

  // A-load register sets (constant-indexed arrays stay in registers)
  float4 rA[8], rB[8];

#define STAGEB(t_, Bb) do {                                                \
    const int kk_ = (t_) * 64 + skc;                                       \
    load16_lds(d.W + (size_t)wrow0 * DMODEL + kk_,      &Bb[0][0][0] + woff0); \
    load16_lds(d.W + (size_t)wrow1 * DMODEL + kk_,      &Bb[0][0][0] + woff1); \
    load16_lds(d.W + (size_t)wrow0 * DMODEL + kk_ + 32, &Bb[1][0][0] + woff0); \
    load16_lds(d.W + (size_t)wrow1 * DMODEL + kk_ + 32, &Bb[1][0][0] + woff1); \
  } while (0)

#define ISSUEA(P, t_) do {                                                 \
    const size_t r0_ = (size_t)arow0 * DMODEL + (t_) * 64 + skc;           \
    const size_t r1_ = (size_t)arow1 * DMODEL + (t_) * 64 + skc;           \
    P[0] = *(const float4*)&d.A[r0_];      P[1] = *(const float4*)&d.A[r0_ + 4];  \
    P[2] = *(const float4*)&d.A[r1_];      P[3] = *(const float4*)&d.A[r1_ + 4];  \
    P[4] = *(const float4*)&d.A[r0_ + 32]; P[5] = *(const float4*)&d.A[r0_ + 36]; \
    P[6] = *(const float4*)&d.A[r1_ + 32]; P[7] = *(const float4*)&d.A[r1_ + 36]; \
  } while (0)

#define WRITEA(P, Ab) do {                                                 \
    unsigned* wp_;                                                         \
    wp_ = (unsigned*)(&Ab[0][0][0]) + wd0;                                 \
    wp_[0] = pack2_bf16(P[0].x, P[0].y); wp_[1] = pack2_bf16(P[0].z, P[0].w); \
    wp_[2] = pack2_bf16(P[1].x, P[1].y); wp_[3] = pack2_bf16(P[1].z, P[1].w); \
    wp_ = (unsigned*)(&Ab[0][0][0]) + wd1;                                 \
    wp_[0] = pack2_bf16(P[2].x, P[2].y); wp_[1] = pack2_bf16(P[2].z, P[2].w); \
    wp_[2] = pack2_bf16(P[3].x, P[3].y); wp_[3] = pack2_bf16(P[3].z, P[3].w); \
    wp_ = (unsigned*)(&Ab[1][0][0]) + wd0;                                 \
    wp_[0] = pack2_bf16(P[4].x, P[4].y); wp_[1] = pack2_bf16(P[4].z, P[4].w); \
    wp_[2] = pack2_bf16(P[5].x, P[5].y); wp_[3] = pack2_bf16(P[5].z, P[5].w); \
    wp_ = (unsigned*)(&Ab[1][0][0]) + wd1;                                 \
    wp_[0] = pack2_bf16(P[6].x, P[6].y); wp_[1] = pack2_bf16(P[6].z, P[6].w); \
    wp_[2] = pack2_bf16(P[7].x, P[7].y); wp_[3] = pack2_bf16(P[7].z, P[7].w); \
  } while (0)

#define COMPUTE256(Ab, Bb) do {                                            \
    _Pragma("unroll")                                                      \
    for (int ks = 0; ks < 2; ++ks) {                                       \
      const unsigned short* Ap = &Ab[ks][0][0];                            \
      const unsigned short* Bp = &Bb[ks][0][0];                            \
      short8 a_[8], b_[4];                                                 \
      _Pragma("unroll")                                                    \
      for (int mi = 0; mi < 8; ++mi)                                       \
        a_[mi] = *(const short8*)&Ap[(wr * 128 + mi * 16 + m16) * 32 + qx * 8]; \
      _Pragma("unroll")                                                    \
      for (int nj = 0; nj < 4; ++nj)                                       \
        b_[nj] = *(const short8*)&Bp[(wc * 64 + nj * 16 + m16) * 32 + qx * 8]; \
      __builtin_amdgcn_s_setprio(1);                                       \
      _Pragma("unroll")                                                    \
      for (int mi = 0; mi < 8; ++mi)                                       \
        _Pragma("unroll")                                                  \
        for (int nj = 0; nj < 4; ++nj)                                     \
          acc[mi][nj] = __builtin_amdgcn_mfma_f32_16x16x32_bf16(           \
              a_[mi], b_[nj], acc[mi][nj], 0, 0, 0);                       \
      __builtin_amdgcn_s_setprio(0);                                       \
    }                                                                      \
  } while (0)

#define TILE(P, Ab, Bb, VM)                                                \
    asm volatile("s_waitcnt vmcnt(" #VM ")" ::: "memory");                 \
    WRITEA(P, Ab);                                                         \
    asm volatile("s_waitcnt lgkmcnt(0)" ::: "memory");                     \
    __builtin_amdgcn_s_barrier();                                          \
    __builtin_amdgcn_sched_barrier(0);                                     \
    COMPUTE256(Ab, Bb);                                                    \
    __builtin_amdgcn_s_barrier();                                          \
    __builtin_amdgcn_sched_barrier(0);

  // prologue: G(0) into set rA/buf0, G(1) into set rB/buf1
  STAGEB(0, Bs[0]); ISSUEA(rA, 0);
  STAGEB(1, Bs[1]); ISSUEA(rB, 1);

#pragma unroll 1
  for (int g = 0; g < 5; ++g) {      // tiles 0..9
    TILE(rA, As[0], Bs[0], 12)
    STAGEB(2 * g + 2, Bs[0]); ISSUEA(rA, 2 * g + 2);
    TILE(rB, As[1], Bs[1], 12)
    STAGEB(2 * g + 3, Bs[1]); ISSUEA(rB, 2 * g + 3);
  }
  // epilogue: tiles 10, 11; drain 12 -> 0
  TILE(rA, As[0], Bs[0], 12)
  TILE(rB, As[1], Bs[1], 0)

#undef STAGEB
#undef ISSUEA
#undef WRITEA
#undef COMPUTE256
#undef TILE

  float bv[4]; int bcol[4];
#pragma unroll
  for (int nj = 0; nj < 4; ++nj) {
    bcol[nj] = bn + wc * 64 + nj * 16 + m16;
    bv[nj] = d.bias[bcol[nj]];
  }
  if (d.obf) {
    unsigned short* Cb = (unsigned short*)d.C;
#pragma unroll
    for (int mi = 0; mi < 8; ++mi) {
      const int rbase = bm + wr * 128 + mi * 16 + quad * 4;
#pragma unroll
      for (int r = 0; r < 4; ++r) {
        const int row = rbase + r;
#pragma unroll
        for (int nj = 0; nj < 4; ++nj)
          Cb[(size_t)row * DMODEL + bcol[nj]] = bf16_1(acc[mi][nj][r] + bv[nj]);
      }
    }
  } else {
    float* Cf = (float*)d.C;
#pragma unroll
    for (int mi = 0; mi < 8; ++mi) {
      const int rbase = bm + wr * 128 + mi * 16 + quad * 4;
#pragma unroll
      for (int r = 0; r < 4; ++r) {
        const int row = rbase + r;
#pragma unroll
        for (int nj = 0; nj < 4; ++nj)
          Cf[(size_t)row * DMODEL + bcol[nj]] = acc[mi][nj][r] + bv[nj];
      }
    }
  }
}

// ------- Wo GEMM: 64x64 tile, ONE wave per block, barrier-free -----------
__global__ __launch_bounds__(64) void gemmWo(const unsigned short* __restrict__ A,
    const unsigned short* __restrict__ W, const float* __restrict__ bias,
    float* __restrict__ C) {
  __shared__ __attribute__((aligned(16))) unsigned short As[4][64 * 32];
  __shared__ __attribute__((aligned(16))) unsigned short Bs[4][64 * 32];
  const int bid = blockIdx.x;
  const int bm = (bid / 12) * 64, bn = (bid % 12) * 64;
  const int lane = threadIdx.x;
  const int m16 = lane & 15, quad = lane >> 4;
  const int qx = quad ^ ((m16 >> 1) & 3);
  const int srow = lane >> 2;
  const int skc = ((lane & 3) ^ ((lane >> 3) & 3)) * 8;

  f32x4 acc[4][4];
#pragma unroll
  for (int i = 0; i < 4; ++i)
#pragma unroll
    for (int j2 = 0; j2 < 4; ++j2) acc[i][j2] = (f32x4){0.f, 0.f, 0.f, 0.f};

#define STAGEW(s_, t_) do {                                                \
    const int kk_ = (t_) * 32 + skc;                                       \
    _Pragma("unroll")                                                      \
    for (int i_ = 0; i_ < 4; ++i_) {                                       \
      load16_lds(A + (size_t)(bm + 16 * i_ + srow) * DMODEL + kk_,         \
                 &As[s_][i_ * 16 * 32]);                                   \
      load16_lds(W + (size_t)(bn + 16 * i_ + srow) * DMODEL + kk_,         \
                 &Bs[s_][i_ * 16 * 32]);                                   \
    }                                                                      \
  } while (0)

#define COMPUTEW(s_) do {                                                  \
    short8 a_[4], b_[4];                                                   \
    _Pragma("unroll")                                                      \
    for (int mi = 0; mi < 4; ++mi)                                         \
      a_[mi] = *(const short8*)&As[s_][(mi * 16 + m16) * 32 + qx * 8];     \
    _Pragma("unroll")                                                      \
    for (int nj = 0; nj < 4; ++nj)                                         \
      b_[nj] = *(const short8*)&Bs[s_][(nj * 16 + m16) * 32 + qx * 8];     \
    _Pragma("unroll")                                                      \
    for (int mi = 0; mi < 4; ++mi)                                         \
      _Pragma("unroll")                                                    \
      for (int nj = 0; nj < 4; ++nj)                                       \
        acc[mi][nj] = __builtin_amdgcn_mfma_f32_16x16x32_bf16(             \
            a_[mi], b_[nj], acc[mi][nj], 0, 0, 0);                         \
  } while (0)

  STAGEW(0, 0); STAGEW(1, 1); STAGEW(2, 2); STAGEW(3, 3);

#pragma unroll 1
  for (int ts = 0; ts < NSTEP - 4; ++ts) {
    asm volatile("s_waitcnt vmcnt(24)" ::: "memory");  // step ts's 8 loads done
    __builtin_amdgcn_sched_barrier(0);
    COMPUTEW(ts & 3);
    asm volatile("s_waitcnt lgkmcnt(0)" ::: "memory"); // ds_reads drained
    __builtin_amdgcn_sched_barrier(0);
    STAGEW(ts & 3, ts + 4);
  }
  asm volatile("s_waitcnt vmcnt(24)" ::: "memory");
  __builtin_amdgcn_sched_barrier(0);
  COMPUTEW(0);
  asm volatile("s_waitcnt vmcnt(16)" ::: "memory");
  __builtin_amdgcn_sched_barrier(0);
  COMPUTEW(1);
  asm volatile("s_waitcnt vmcnt(8)" ::: "memory");
  __builtin_amdgcn_sched_barrier(0);
  COMPUTEW(2);
  asm volatile("s_waitcnt vmcnt(0)" ::: "memory");
  __builtin_amdgcn_sched_barrier(0);
  COMPUTEW(3);

#undef STAGEW
#undef COMPUTEW

  float bv[4]; int bcol[4];
#pragma unroll
  for (int nj = 0; nj < 4; ++nj) {
    bcol[nj] = bn + nj * 16 + m16;
    bv[nj] = bias[bcol[nj]];
  }
#pragma unroll
  for (int mi = 0; mi < 4; ++mi) {
    const int rbase = bm + mi * 16 + quad * 4;
#pragma unroll
    for (int r = 0; r < 4; ++r) {
      const int row = rbase + r;
#pragma unroll
      for (int nj = 0; nj < 4; ++nj)
        C[(size_t)row * DMODEL + bcol[nj]] = acc[mi][nj][r] + bv[nj];
    }
  }
}

__device__ __forceinline__ float allreduce64(float x) {
#pragma unroll
  for (int m = 1; m < 64; m <<= 1) x += __shfl_xor(x, m, 64);
  return x;
}

// merged attention (k/v are bf16), 4-wave workgroups: wave wid = head
// blockIdx.y*4+wid. WG x < nfx: 4 features per wave (R13 batched fast path).
// WG x >= nfx: split-K pass-1 piece (x-nfx) for fully-masked features.
__global__ __launch_bounds__(256) void attn_all(const float* __restrict__ q,
    const unsigned short* __restrict__ k, const unsigned short* __restrict__ v,
    const int* __restrict__ left, const int* __restrict__ right,
    const int* __restrict__ nvalid, const int* __restrict__ ids,
    const int* __restrict__ padp, unsigned short* __restrict__ out,
    const int* __restrict__ fullist, const int* __restrict__ nfullp,
    int n, int f, int P, int nfx, float* __restrict__ pm,
    float* __restrict__ pl, float* __restrict__ pacc) {
  __shared__ float q_lds[4][8 * 64];
  __shared__ float w_lds[4][64 * 8];
  const int x = blockIdx.x, lane = threadIdx.x & 63, wid = threadIdx.x >> 6;
  const int h = blockIdx.y * 4 + wid;

  if (x < nfx) {
    // ---- 4 normal-segment features per wave ----
    const int f0 = x * 4;
    const int off = h * 64 + lane;
    const int pad = *padp;
    int L0[4], R0[4], nv[4];
#pragma unroll
    for (int ff = 0; ff < 4; ++ff) {
      L0[ff] = left[f0 + ff];
      R0[ff] = right[f0 + ff];
      nv[ff] = nvalid[f0 + ff];
    }
    bool allfast = true;
#pragma unroll
    for (int ff = 0; ff < 4; ++ff) allfast &= (R0[ff] - L0[ff] == 8);
    if (allfast) {
      float qv[4], kv[4][8], vv[4][8];
      unsigned live[4];
#pragma unroll
      for (int ff = 0; ff < 4; ++ff) {
        qv[ff] = q[(size_t)(f0 + ff) * DMODEL + off];
        live[ff] = 0;
#pragma unroll
        for (int p = 0; p < 8; ++p) {
          kv[ff][p] = b2f(k[(size_t)(L0[ff] + p) * DMODEL + off]);
          vv[ff][p] = b2f(v[(size_t)(L0[ff] + p) * DMODEL + off]);
          live[ff] |= (ids[L0[ff] + p] != pad ? 1u : 0u) << p;
        }
      }
      float s[4][8];
#pragma unroll
      for (int ff = 0; ff < 4; ++ff)
#pragma unroll
        for (int p = 0; p < 8; ++p) s[ff][p] = qv[ff] * kv[ff][p];
#pragma unroll
      for (int m_ = 1; m_ < 64; m_ <<= 1)
#pragma unroll
        for (int ff = 0; ff < 4; ++ff)
#pragma unroll
          for (int p = 0; p < 8; ++p) s[ff][p] += __shfl_xor(s[ff][p], m_, 64);
#pragma unroll
      for (int ff = 0; ff < 4; ++ff) {
        if (nv[ff] == 0) continue;   // handled by the split-K/comb path
        float mx = -1e30f;
#pragma unroll
        for (int p = 0; p < 8; ++p) {
          s[ff][p] = ((live[ff] >> p) & 1u) ? s[ff][p] * 0.125f : -1e30f;
          mx = fmaxf(mx, s[ff][p]);
        }
        float l = 0.f, acc = 0.f;
#pragma unroll
        for (int p = 0; p < 8; ++p) {
          float w = __expf(s[ff][p] - mx);
          l += w;
          acc += w * vv[ff][p];
        }
        out[(size_t)(f0 + ff) * DMODEL + off] = bf16_1(acc / l);
      }
      return;
    }
    // slow path: per-feature serial online softmax (rare)
    for (int ff = 0; ff < 4; ++ff) {
      if (nv[ff] == 0) continue;
      const float qv = q[(size_t)(f0 + ff) * DMODEL + off];
      float m = -1e30f, l = 0.f, acc = 0.f;
      for (int p = L0[ff]; p < R0[ff]; ++p) {
        if (ids[p] == pad) continue;
        float s = allreduce64(qv * b2f(k[(size_t)p * DMODEL + off])) * 0.125f;
        float mn = fmaxf(m, s);
        float al = __expf(m - mn);
        float w = __expf(s - mn);
        l = l * al + w;
        acc = acc * al + w * b2f(v[(size_t)p * DMODEL + off]);
        m = mn;
      }
      out[(size_t)(f0 + ff) * DMODEL + off] = bf16_1(acc / l);
    }
    return;
  }

  // ---- fully-masked features: split-K pass 1, wave = (h, piece) ----
  const int nfull = *nfullp;
  if (nfull == 0) return;
  const int piece = x - nfx;
  const int pk = n / P;                    // keys per piece (multiple of 64)

  // per-wave q staging (wave-synchronous; no block barrier needed)
#pragma unroll
  for (int fl = 0; fl < 8; ++fl)
    q_lds[wid][fl * 64 + lane] =
        (fl < nfull) ? q[(size_t)fullist[fl] * DMODEL + h * 64 + lane] : 0.f;

  float m[8], l[8], acc[8];
#pragma unroll
  for (int f_ = 0; f_ < 8; ++f_) { m[f_] = -1e30f; l[f_] = 0.f; acc[f_] = 0.f; }

  for (int c = 0; c < pk; c += 64) {
    const int pc = piece * pk + c;
    float s[8];
#pragma unroll
    for (int f_ = 0; f_ < 8; ++f_) s[f_] = 0.f;
    const u16x8* kp = (const u16x8*)(k + (size_t)(pc + lane) * DMODEL + h * 64);
#pragma unroll 1
    for (int g = 0; g < 2; ++g) {
      u16x8 u0 = kp[g * 4 + 0], u1 = kp[g * 4 + 1], u2 = kp[g * 4 + 2],
            u3 = kp[g * 4 + 3];
      float4 kv0 = lo4(u0), kv1 = hi4(u0), kv2 = lo4(u1), kv3 = hi4(u1),
             kv4 = lo4(u2), kv5 = hi4(u2), kv6 = lo4(u3), kv7 = hi4(u3);
      const float4* qb = (const float4*)&q_lds[wid][g * 32];
#pragma unroll
      for (int f_ = 0; f_ < 8; ++f_) {
        float4 q0 = qb[f_ * 16 + 0], q1 = qb[f_ * 16 + 1], q2 = qb[f_ * 16 + 2],
               q3 = qb[f_ * 16 + 3], q4 = qb[f_ * 16 + 4], q5 = qb[f_ * 16 + 5],
               q6 = qb[f_ * 16 + 6], q7 = qb[f_ * 16 + 7];
        float acc0 = q0.x * kv0.x + q0.y * kv0.y + q0.z * kv0.z + q0.w * kv0.w;
        acc0 += q1.x * kv1.x + q1.y * kv1.y + q1.z * kv1.z + q1.w * kv1.w;
        acc0 += q2.x * kv2.x + q2.y * kv2.y + q2.z * kv2.z + q2.w * kv2.w;
        acc0 += q3.x * kv3.x + q3.y * kv3.y + q3.z * kv3.z + q3.w * kv3.w;
        acc0 += q4.x * kv4.x + q4.y * kv4.y + q4.z * kv4.z + q4.w * kv4.w;
        acc0 += q5.x * kv5.x + q5.y * kv5.y + q5.z * kv5.z + q5.w * kv5.w;
        acc0 += q6.x * kv6.x + q6.y * kv6.y + q6.z * kv6.z + q6.w * kv6.w;
        acc0 += q7.x * kv7.x + q7.y * kv7.y + q7.z * kv7.z + q7.w * kv7.w;
        s[f_] += acc0;
      }
    }
    float mx[8];
#pragma unroll
    for (int f_ = 0; f_ < 8; ++f_) mx[f_] = s[f_] * 0.125f;
#pragma unroll
    for (int f_ = 0; f_ < 8; ++f_) s[f_] = mx[f_];
#pragma unroll
    for (int st = 1; st < 64; st <<= 1)
#pragma unroll
      for (int f_ = 0; f_ < 8; ++f_) mx[f_] = fmaxf(mx[f_], __shfl_xor(mx[f_], st, 64));
    float alpha[8], w[8], sum[8];
#pragma unroll
    for (int f_ = 0; f_ < 8; ++f_) {
      float mn = fmaxf(m[f_], mx[f_]);
      alpha[f_] = __expf(m[f_] - mn);
      w[f_] = __expf(s[f_] - mn);
      m[f_] = mn;
      sum[f_] = w[f_];
    }
#pragma unroll
    for (int st = 1; st < 64; st <<= 1)
#pragma unroll
      for (int f_ = 0; f_ < 8; ++f_) sum[f_] += __shfl_xor(sum[f_], st, 64);
#pragma unroll
    for (int f_ = 0; f_ < 8; ++f_) l[f_] = l[f_] * alpha[f_] + sum[f_];
    *(float4*)&w_lds[wid][lane * 8]     = make_float4(w[0], w[1], w[2], w[3]);
    *(float4*)&w_lds[wid][lane * 8 + 4] = make_float4(w[4], w[5], w[6], w[7]);
#pragma unroll
    for (int f_ = 0; f_ < 8; ++f_) acc[f_] *= alpha[f_];
    const unsigned short* vb = v + (size_t)pc * DMODEL + h * 64 + lane;
#pragma unroll 4
    for (int kk = 0; kk < 64; ++kk) {
      float vd = b2f(vb[(size_t)kk * DMODEL]);
      float4 wa = *(const float4*)&w_lds[wid][kk * 8];
      float4 wb = *(const float4*)&w_lds[wid][kk * 8 + 4];
      acc[0] += wa.x * vd; acc[1] += wa.y * vd; acc[2] += wa.z * vd; acc[3] += wa.w * vd;
      acc[4] += wb.x * vd; acc[5] += wb.y * vd; acc[6] += wb.z * vd; acc[7] += wb.w * vd;
    }
  }

  for (int f_ = 0; f_ < nfull; ++f_) {
    size_t idx = ((size_t)f_ * NHEADS + h) * P + piece;
    if (lane == 0) { pm[idx] = m[f_]; pl[idx] = l[f_]; }
    pacc[idx * 64 + lane] = acc[f_];
  }
}

// Split-K pass 2: merge the P partials per (full-feature, head). Writes bf16.
__global__ __launch_bounds__(256) void attn_full_comb(
    const int* __restrict__ fullist, const int* __restrict__ nfullp,
    int P, const float* __restrict__ pm, const float* __restrict__ pl,
    const float* __restrict__ pacc, unsigned short* __restrict__ out) {
  const int fl = blockIdx.x, h = blockIdx.y;
  if (fl >= *nfullp) return;
  const int feat = fullist[fl];
  const int t = threadIdx.x, lane = t & 63, wv = t >> 6;
  const size_t base = ((size_t)fl * NHEADS + h) * P;

  __shared__ float s_pm[128];    // P <= 128
  __shared__ float s_sc[128];
  __shared__ float s_red[4];
  __shared__ float s_part[4][64];

  for (int sp = t; sp < P; sp += 256) s_pm[sp] = pm[base + sp];
  __syncthreads();
  float mloc = -1e30f;
  for (int sp = t; sp < P; sp += 256) mloc = fmaxf(mloc, s_pm[sp]);
#pragma unroll
  for (int st = 1; st < 64; st <<= 1) mloc = fmaxf(mloc, __shfl_xor(mloc, st, 64));
  if (lane == 0) s_red[wv] = mloc;
  __syncthreads();
  const float M = fmaxf(fmaxf(s_red[0], s_red[1]), fmaxf(s_red[2], s_red[3]));
  __syncthreads();
  float lloc = 0.f;
  for (int sp = t; sp < P; sp += 256) {
    float sc = __expf(s_pm[sp] - M);
    s_sc[sp] = sc;
    lloc += pl[base + sp] * sc;
  }
#pragma unroll
  for (int st = 1; st < 64; st <<= 1) lloc += __shfl_xor(lloc, st, 64);
  if (lane == 0) s_red[wv] = lloc;
  __syncthreads();
  const float Lt = s_red[0] + s_red[1] + s_red[2] + s_red[3];
  float At = 0.f;
  for (int sp = wv; sp < P; sp += 4)
    At += pacc[(base + sp) * 64 + lane] * s_sc[sp];
  s_part[wv][lane] = At;
  __syncthreads();
  if (wv == 0) {
    float tot = s_part[0][lane] + s_part[1][lane] + s_part[2][lane] + s_part[3][lane];
    out[(size_t)feat * DMODEL + h * 64 + lane] = bf16_1(tot / Lt);
  }
}

extern "C" void kernel_launch(void* const* d_in, const int* in_sizes, int n_in,
                              void* d_out, int out_size, void* d_ws, size_t ws_size,
                              hipStream_t stream) {
  const float* x_qk = (const float*)d_in[0];
  const float* x_v  = (const float*)d_in[1];
  const int* qm     = (const int*)d_in[2];
  const int* ids    = (const int*)d_in[3];
  const int* padp   = (const int*)d_in[4];
  const float* Wq = (const float*)d_in[5];
  const float* bq = (const float*)d_in[6];
  const float* Wk = (const float*)d_in[7];
  const float* bk = (const float*)d_in[8];
  const float* Wv = (const float*)d_in[9];
  const float* bv = (const float*)d_in[10];
  const float* Wo = (const float*)d_in[11];
  const float* bo = (const float*)d_in[12];

  const int n = in_sizes[0] / DMODEL;   // 8192
  const int f = out_size / DMODEL;      // 1024

  // ws: kfh,vfh bf16 | qf f32 | af bf16 | Wbf x4 | ints | split partials
  unsigned short* kfh = (unsigned short*)d_ws;
  unsigned short* vfh = kfh + (size_t)n * DMODEL;
  float* qf = (float*)(vfh + (size_t)n * DMODEL);
  unsigned short* af = (unsigned short*)(qf + (size_t)f * DMODEL);
  unsigned short* wqb = af + (size_t)f * DMODEL;
  unsigned short* wkb = wqb + DMODEL * DMODEL;
  unsigned short* wvb = wkb + DMODEL * DMODEL;
  unsigned short* wob = wvb + DMODEL * DMODEL;
  int* left     = (int*)(wob + DMODEL * DMODEL);
  int* right    = left + f;
  int* nvalid   = right + f;
  int* fullrank = nvalid + f;
  int* fullist  = fullrank + f;
  int* nfull    = fullist + MAXFULL;
  size_t off_bytes = ((size_t)((char*)(nfull + 1) - (char*)d_ws) + 255) & ~(size_t)255;
  int P = 128;
  while (P > 16) {
    size_t need = (size_t)MAXFULL * NHEADS * P * 66 * sizeof(float);
    if (off_bytes + need <= ws_size && (n / P) % 64 == 0 && n % P == 0) break;
    P >>= 1;
  }
  float* pm = (float*)((char*)d_ws + off_bytes);
  float* pl = pm + (size_t)MAXFULL * NHEADS * P;
  float* pacc = pl + (size_t)MAXFULL * NHEADS * P;

  convAll<<<257, 256, 0, stream>>>(Wq, Wk, Wv, Wo, (unsigned*)wqb,
                                   (unsigned*)wkb, (unsigned*)wvb,
                                   (unsigned*)wob, DMODEL * DMODEL,
                                   qm, ids, padp, n, f, left, right, nvalid,
                                   fullrank, fullist, nfull);

  // main QKV GEMM at 256x256: K (96) | V (96) | Q-gather (12) = 204 blocks
  const int TKV256 = 3 * (n / 256);   // 96
  const int TF256  = 3 * (f / 256);   // 12
  GSeg g0 = { x_qk, wkb, bk, nullptr, (void*)kfh, 0,           TKV256, 1 };
  GSeg g1 = { x_v,  wvb, bv, nullptr, (void*)vfh, TKV256,      TKV256, 1 };
  GSeg g2 = { x_qk, wqb, bq, left,    (void*)qf,  2 * TKV256,  TF256,  0 };
  gemm256<<<2 * TKV256 + TF256, 512, 0, stream>>>(g0, g1, g2);

  const int nfx = f / 4;              // 256 feature WGs (4 features per wave)
  attn_all<<<dim3(nfx + P, NHEADS / 4), 256, 0, stream>>>(qf, kfh, vfh, left,
                                                          right, nvalid, ids,
                                                          padp, af, fullist,
                                                          nfull, n, f, P, nfx,
                                                          pm, pl, pacc);
  attn_full_comb<<<dim3(MAXFULL, NHEADS), 256, 0, stream>>>(fullist, nfull, P,
                                                            pm, pl, pacc, af);

  gemmWo<<<(f / 64) * (DMODEL / 64), 64, 0, stream>>>(af, wob, bo, (float*)d_out);
}

// Round 17
// 213.467 us; speedup vs baseline: 1.9191x; 1.9191x over previous
//
#include <hip/hip_runtime.h>

#define DMODEL 768
#define NHEADS 12
#define MAXFULL 16
#define NSTEP 24   // DMODEL / 32

typedef __attribute__((ext_vector_type(8))) short short8;
typedef __attribute__((ext_vector_type(4))) float f32x4;
typedef __attribute__((ext_vector_type(8))) unsigned short u16x8;

__device__ __forceinline__ unsigned pack2_bf16(float a, float b) {
  unsigned ua = __float_as_uint(a), ub = __float_as_uint(b);
  ua = (ua + 0x7fffu + ((ua >> 16) & 1u)) >> 16;
  ub = (ub + 0x7fffu + ((ub >> 16) & 1u)) & 0xffff0000u;
  return ua | ub;
}
__device__ __forceinline__ unsigned short bf16_1(float a) {
  unsigned ua = __float_as_uint(a);
  return (unsigned short)((ua + 0x7fffu + ((ua >> 16) & 1u)) >> 16);
}
__device__ __forceinline__ float b2f(unsigned short u) {
  return __uint_as_float(((unsigned)u) << 16);
}
__device__ __forceinline__ float4 lo4(u16x8 u) {
  return make_float4(b2f(u[0]), b2f(u[1]), b2f(u[2]), b2f(u[3]));
}
__device__ __forceinline__ float4 hi4(u16x8 u) {
  return make_float4(b2f(u[4]), b2f(u[5]), b2f(u[6]), b2f(u[7]));
}

// direct global->LDS DMA, 16 B per lane; LDS dest = wave-uniform base + lane*16
__device__ __forceinline__ void load16_lds(const void* g, void* l) {
  __builtin_amdgcn_global_load_lds(
      (const __attribute__((address_space(1))) unsigned int*)g,
      (__attribute__((address_space(3))) unsigned int*)l, 16, 0, 0);
}

// fused: f32->bf16 conversion (blocks 0..nb-1) + segment build (last block).
// fullist compaction: order-preserving PARALLEL prefix-scan (deterministic).
__global__ __launch_bounds__(256) void convAll(const float* __restrict__ w0,
    const float* __restrict__ w1, const float* __restrict__ w2,
    const float* __restrict__ w3, unsigned* __restrict__ o0,
    unsigned* __restrict__ o1, unsigned* __restrict__ o2,
    unsigned* __restrict__ o3, int wcount,
    const float* __restrict__ x0, const float* __restrict__ x1,
    unsigned* __restrict__ xo0, unsigned* __restrict__ xo1, int xcount,
    const int* __restrict__ qm, const int* __restrict__ ids,
    const int* __restrict__ padp, int n, int f, int* __restrict__ left,
    int* __restrict__ right, int* __restrict__ nvalid,
    int* __restrict__ fullrank, int* __restrict__ fullist,
    int* __restrict__ nfull) {
  __shared__ int cnt[256];
  const int t = threadIdx.x;
  if (blockIdx.x == gridDim.x - 1) {
    // ---- segment build (one block, 256 threads) ----
    const int per = (n + 255) >> 8;
    const int base = t * per;
    int c = 0;
    for (int i = 0; i < per; ++i) {
      int p = base + i;
      if (p < n && qm[p] != 0) ++c;
    }
    cnt[t] = c;
    __syncthreads();
    for (int off = 1; off < 256; off <<= 1) {
      int v = (t >= off) ? cnt[t - off] : 0;
      __syncthreads();
      cnt[t] += v;
      __syncthreads();
    }
    int r = cnt[t] - c;  // exclusive prefix
    for (int i = 0; i < per; ++i) {
      int p = base + i;
      if (p < n && qm[p] != 0) {
        if (r < f) left[r] = p;
        ++r;
      }
    }
    __syncthreads();
    const int pad = *padp;
    for (int i = t; i < f; i += 256) {
      int L0 = left[i];
      int R0 = (i + 1 < f) ? left[i + 1] : n;
      right[i] = R0;
      int cv = 0;
      for (int p = L0; p < R0; ++p) cv += (ids[p] != pad) ? 1 : 0;
      nvalid[i] = cv;
      fullrank[i] = -1;
    }
    __syncthreads();
    // order-preserving parallel compaction of {i : nvalid[i]==0}
    const int perf = (f + 255) >> 8;
    const int zbase = t * perf;
    int zc = 0;
    for (int i = 0; i < perf; ++i) {
      int idx = zbase + i;
      if (idx < f && nvalid[idx] == 0) ++zc;
    }
    cnt[t] = zc;
    __syncthreads();
    for (int off = 1; off < 256; off <<= 1) {
      int v = (t >= off) ? cnt[t - off] : 0;
      __syncthreads();
      cnt[t] += v;
      __syncthreads();
    }
    int zr = cnt[t] - zc;  // exclusive prefix (feature-ordered)
    for (int i = 0; i < perf; ++i) {
      int idx = zbase + i;
      if (idx < f && nvalid[idx] == 0) {
        if (zr < MAXFULL) { fullist[zr] = idx; fullrank[idx] = zr; }
        ++zr;
      }
    }
    __syncthreads();
    if (t == 0) *nfull = (cnt[255] < MAXFULL) ? cnt[255] : MAXFULL;
    return;
  }
  // ---- conversion (grid-stride over nb blocks) ----
  const int nb = gridDim.x - 1;
  const int nvw = wcount >> 2;
  const float* src[4] = {w0, w1, w2, w3};
  unsigned* dst[4] = {o0, o1, o2, o3};
  for (int idx = blockIdx.x * 256 + t; idx < 4 * nvw; idx += nb * 256) {
    int m = idx / nvw, r = idx - m * nvw;
    float4 v = ((const float4*)src[m])[r];
    dst[m][2 * r]     = pack2_bf16(v.x, v.y);
    dst[m][2 * r + 1] = pack2_bf16(v.z, v.w);
  }
  const int nvx = xcount >> 2;
  for (int idx = blockIdx.x * 256 + t; idx < 2 * nvx; idx += nb * 256) {
    int m = idx / nvx, r = idx - m * nvx;
    float4 v = m ? ((const float4*)x1)[r] : ((const float4*)x0)[r];
    unsigned* d = m ? xo1 : xo0;
    d[2 * r]     = pack2_bf16(v.x, v.y);
    d[2 * r + 1] = pack2_bf16(v.z, v.w);
  }
}

struct GSeg {
  const unsigned short* A;   // bf16 activations [*,768]
  const unsigned short* W;   // bf16 weights [col][k]
  const float* bias;
  const int* row_map;        // optional row gather
  void* C;                   // f32 out (obf=0) or bf16 out (obf=1)
  int base;                  // first flat block id of this segment
  int nwg;                   // blocks in this segment
  int obf;                   // 1 -> write bf16
};

typedef unsigned short LdsTile[2][256][32];  // [k-panel][row][32 elems=64B]

// ---------------- 256x256 main GEMM (verified R5 structure + T1) ----------
__global__ __launch_bounds__(512, 2) void gemm256(GSeg g0, GSeg g1, GSeg g2) {
  __shared__ __attribute__((aligned(16))) LdsTile As[2];
  __shared__ __attribute__((aligned(16))) LdsTile Bs[2];
  const int t = threadIdx.x;
  const int id = blockIdx.x;
  const GSeg& d = (id >= g2.base) ? g2 : ((id >= g1.base) ? g1 : g0);
  const int lid = id - d.base;
  // bijective XCD swizzle when nwg % 8 == 0 (K/V segments: 96 -> cpx=12)
  const int j = (d.nwg & 7) == 0 ? (lid & 7) * (d.nwg >> 3) + (lid >> 3) : lid;
  const int bn = (j % 3) * 256;
  const int bm = (j / 3) * 256;
  const int lane = t & 63, wid = t >> 6;
  const int m16 = lane & 15, quad = lane >> 4;
  const int qx = quad ^ ((m16 >> 1) & 3);   // T2 reader involution (64B rows)
  const int wr = wid >> 2, wc = wid & 3;    // 2x4 wave grid

  f32x4 acc[8][4];
#pragma unroll
  for (int i = 0; i < 8; ++i)
#pragma unroll
    for (int j2 = 0; j2 < 4; ++j2) acc[i][j2] = (f32x4){0.f, 0.f, 0.f, 0.f};

  const int srow = wid * 16 + (lane >> 2);                    // 0..127
  const int skc = ((lane & 3) ^ ((lane >> 3) & 3)) * 8;       // T2 source perm
  int arow0, arow1;
  if (d.row_map) {
    arow0 = d.row_map[bm + srow];
    arow1 = d.row_map[bm + 128 + srow];
  } else {
    arow0 = bm + srow;
    arow1 = bm + 128 + srow;
  }
  const int wrow0 = bn + srow, wrow1 = bn + 128 + srow;
  const int woff0 = (wid * 16) * 32;
  const int woff1 = (128 + wid * 16) * 32;

#define STAGE256(t_, Ab, Bb) do {                                          \
    const int kk_ = (t_) * 64 + skc;                                       \
    load16_lds(d.A + (size_t)arow0 * DMODEL + kk_,      &Ab[0][0][0] + woff0); \
    load16_lds(d.A + (size_t)arow1 * DMODEL + kk_,      &Ab[0][0][0] + woff1); \
    load16_lds(d.A + (size_t)arow0 * DMODEL + kk_ + 32, &Ab[1][0][0] + woff0); \
    load16_lds(d.A + (size_t)arow1 * DMODEL + kk_ + 32, &Ab[1][0][0] + woff1); \
    load16_lds(d.W + (size_t)wrow0 * DMODEL + kk_,      &Bb[0][0][0] + woff0); \
    load16_lds(d.W + (size_t)wrow1 * DMODEL + kk_,      &Bb[0][0][0] + woff1); \
    load16_lds(d.W + (size_t)wrow0 * DMODEL + kk_ + 32, &Bb[1][0][0] + woff0); \
    load16_lds(d.W + (size_t)wrow1 * DMODEL + kk_ + 32, &Bb[1][0][0] + woff1); \
  } while (0)

#define COMPUTE256(Ab, Bb) do {                                            \
    _Pragma("unroll")                                                      \
    for (int ks = 0; ks < 2; ++ks) {                                       \
      const unsigned short* Ap = &Ab[ks][0][0];                            \
      const unsigned short* Bp = &Bb[ks][0][0];                            \
      short8 a_[8], b_[4];                                                 \
      _Pragma("unroll")                                                    \
      for (int mi = 0; mi < 8; ++mi)                                       \
        a_[mi] = *(const short8*)&Ap[(wr * 128 + mi * 16 + m16) * 32 + qx * 8]; \
      _Pragma("unroll")                                                    \
      for (int nj = 0; nj < 4; ++nj)                                       \
        b_[nj] = *(const short8*)&Bp[(wc * 64 + nj * 16 + m16) * 32 + qx * 8]; \
      __builtin_amdgcn_s_setprio(1);                                       \
      _Pragma("unroll")                                                    \
      for (int mi = 0; mi < 8; ++mi)                                       \
        _Pragma("unroll")                                                  \
        for (int nj = 0; nj < 4; ++nj)                                     \
          acc[mi][nj] = __builtin_amdgcn_mfma_f32_16x16x32_bf16(           \
              a_[mi], b_[nj], acc[mi][nj], 0, 0, 0);                       \
      __builtin_amdgcn_s_setprio(0);                                       \
    }                                                                      \
  } while (0)

  STAGE256(0, As[0], Bs[0]);
  STAGE256(1, As[1], Bs[1]);

#pragma unroll 1
  for (int g = 0; g < 5; ++g) {
    asm volatile("s_waitcnt vmcnt(8)" ::: "memory");
    __builtin_amdgcn_s_barrier();
    __builtin_amdgcn_sched_barrier(0);
    COMPUTE256(As[0], Bs[0]);
    __builtin_amdgcn_s_barrier();
    __builtin_amdgcn_sched_barrier(0);
    STAGE256(2 * g + 2, As[0], Bs[0]);
    asm volatile("s_waitcnt vmcnt(8)" ::: "memory");
    __builtin_amdgcn_s_barrier();
    __builtin_amdgcn_sched_barrier(0);
    COMPUTE256(As[1], Bs[1]);
    __builtin_amdgcn_s_barrier();
    __builtin_amdgcn_sched_barrier(0);
    STAGE256(2 * g + 3, As[1], Bs[1]);
  }
  asm volatile("s_waitcnt vmcnt(8)" ::: "memory");
  __builtin_amdgcn_s_barrier();
  __builtin_amdgcn_sched_barrier(0);
  COMPUTE256(As[0], Bs[0]);
  asm volatile("s_waitcnt vmcnt(0)" ::: "memory");
  __builtin_amdgcn_s_barrier();
  __builtin_amdgcn_sched_barrier(0);
  COMPUTE256(As[1], Bs[1]);

#undef STAGE256
#undef COMPUTE256

  float bv[4]; int bcol[4];
#pragma unroll
  for (int nj = 0; nj < 4; ++nj) {
    bcol[nj] = bn + wc * 64 + nj * 16 + m16;
    bv[nj] = d.bias[bcol[nj]];
  }
  if (d.obf) {
    unsigned short* Cb = (unsigned short*)d.C;
#pragma unroll
    for (int mi = 0; mi < 8; ++mi) {
      const int rbase = bm + wr * 128 + mi * 16 + quad * 4;
#pragma unroll
      for (int r = 0; r < 4; ++r) {
        const int row = rbase + r;
#pragma unroll
        for (int nj = 0; nj < 4; ++nj)
          Cb[(size_t)row * DMODEL + bcol[nj]] = bf16_1(acc[mi][nj][r] + bv[nj]);
      }
    }
  } else {
    float* Cf = (float*)d.C;
#pragma unroll
    for (int mi = 0; mi < 8; ++mi) {
      const int rbase = bm + wr * 128 + mi * 16 + quad * 4;
#pragma unroll
      for (int r = 0; r < 4; ++r) {
        const int row = rbase + r;
#pragma unroll
        for (int nj = 0; nj < 4; ++nj)
          Cf[(size_t)row * DMODEL + bcol[nj]] = acc[mi][nj][r] + bv[nj];
      }
    }
  }
}

// ------- Wo GEMM: 64x64 tile, ONE wave per block, barrier-free -----------
__global__ __launch_bounds__(64) void gemmWo(const unsigned short* __restrict__ A,
    const unsigned short* __restrict__ W, const float* __restrict__ bias,
    float* __restrict__ C) {
  __shared__ __attribute__((aligned(16))) unsigned short As[4][64 * 32];
  __shared__ __attribute__((aligned(16))) unsigned short Bs[4][64 * 32];
  const int bid = blockIdx.x;
  const int bm = (bid / 12) * 64, bn = (bid % 12) * 64;
  const int lane = threadIdx.x;
  const int m16 = lane & 15, quad = lane >> 4;
  const int qx = quad ^ ((m16 >> 1) & 3);
  const int srow = lane >> 2;
  const int skc = ((lane & 3) ^ ((lane >> 3) & 3)) * 8;

  f32x4 acc[4][4];
#pragma unroll
  for (int i = 0; i < 4; ++i)
#pragma unroll
    for (int j2 = 0; j2 < 4; ++j2) acc[i][j2] = (f32x4){0.f, 0.f, 0.f, 0.f};

#define STAGEW(s_, t_) do {                                                \
    const int kk_ = (t_) * 32 + skc;                                       \
    _Pragma("unroll")                                                      \
    for (int i_ = 0; i_ < 4; ++i_) {                                       \
      load16_lds(A + (size_t)(bm + 16 * i_ + srow) * DMODEL + kk_,         \
                 &As[s_][i_ * 16 * 32]);                                   \
      load16_lds(W + (size_t)(bn + 16 * i_ + srow) * DMODEL + kk_,         \
                 &Bs[s_][i_ * 16 * 32]);                                   \
    }                                                                      \
  } while (0)

#define COMPUTEW(s_) do {                                                  \
    short8 a_[4], b_[4];                                                   \
    _Pragma("unroll")                                                      \
    for (int mi = 0; mi < 4; ++mi)                                         \
      a_[mi] = *(const short8*)&As[s_][(mi * 16 + m16) * 32 + qx * 8];     \
    _Pragma("unroll")                                                      \
    for (int nj = 0; nj < 4; ++nj)                                         \
      b_[nj] = *(const short8*)&Bs[s_][(nj * 16 + m16) * 32 + qx * 8];     \
    _Pragma("unroll")                                                      \
    for (int mi = 0; mi < 4; ++mi)                                         \
      _Pragma("unroll")                                                    \
      for (int nj = 0; nj < 4; ++nj)                                       \
        acc[mi][nj] = __builtin_amdgcn_mfma_f32_16x16x32_bf16(             \
            a_[mi], b_[nj], acc[mi][nj], 0, 0, 0);                         \
  } while (0)

  STAGEW(0, 0); STAGEW(1, 1); STAGEW(2, 2); STAGEW(3, 3);

#pragma unroll 1
  for (int ts = 0; ts < NSTEP - 4; ++ts) {
    asm volatile("s_waitcnt vmcnt(24)" ::: "memory");  // step ts's 8 loads done
    __builtin_amdgcn_sched_barrier(0);
    COMPUTEW(ts & 3);
    asm volatile("s_waitcnt lgkmcnt(0)" ::: "memory"); // ds_reads drained
    __builtin_amdgcn_sched_barrier(0);
    STAGEW(ts & 3, ts + 4);
  }
  asm volatile("s_waitcnt vmcnt(24)" ::: "memory");
  __builtin_amdgcn_sched_barrier(0);
  COMPUTEW(0);
  asm volatile("s_waitcnt vmcnt(16)" ::: "memory");
  __builtin_amdgcn_sched_barrier(0);
  COMPUTEW(1);
  asm volatile("s_waitcnt vmcnt(8)" ::: "memory");
  __builtin_amdgcn_sched_barrier(0);
  COMPUTEW(2);
  asm volatile("s_waitcnt vmcnt(0)" ::: "memory");
  __builtin_amdgcn_sched_barrier(0);
  COMPUTEW(3);

#undef STAGEW
#undef COMPUTEW

  float bv[4]; int bcol[4];
#pragma unroll
  for (int nj = 0; nj < 4; ++nj) {
    bcol[nj] = bn + nj * 16 + m16;
    bv[nj] = bias[bcol[nj]];
  }
#pragma unroll
  for (int mi = 0; mi < 4; ++mi) {
    const int rbase = bm + mi * 16 + quad * 4;
#pragma unroll
    for (int r = 0; r < 4; ++r) {
      const int row = rbase + r;
#pragma unroll
      for (int nj = 0; nj < 4; ++nj)
        C[(size_t)row * DMODEL + bcol[nj]] = acc[mi][nj][r] + bv[nj];
    }
  }
}

__device__ __forceinline__ float allreduce64(float x) {
#pragma unroll
  for (int m = 1; m < 64; m <<= 1) x += __shfl_xor(x, m, 64);
  return x;
}

// merged attention (k/v are bf16), 4-wave workgroups: wave wid = head
// blockIdx.y*4+wid. WG x < nfx: 4 features per wave (R13 batched fast path).
// WG x >= nfx: split-K pass-1 piece (x-nfx) for fully-masked features.
__global__ __launch_bounds__(256) void attn_all(const float* __restrict__ q,
    const unsigned short* __restrict__ k, const unsigned short* __restrict__ v,
    const int* __restrict__ left, const int* __restrict__ right,
    const int* __restrict__ nvalid, const int* __restrict__ ids,
    const int* __restrict__ padp, unsigned short* __restrict__ out,
    const int* __restrict__ fullist, const int* __restrict__ nfullp,
    int n, int f, int P, int nfx, float* __restrict__ pm,
    float* __restrict__ pl, float* __restrict__ pacc) {
  __shared__ float q_lds[4][8 * 64];
  __shared__ float w_lds[4][64 * 8];
  const int x = blockIdx.x, lane = threadIdx.x & 63, wid = threadIdx.x >> 6;
  const int h = blockIdx.y * 4 + wid;

  if (x < nfx) {
    // ---- 4 normal-segment features per wave ----
    const int f0 = x * 4;
    const int off = h * 64 + lane;
    const int pad = *padp;
    int L0[4], R0[4], nv[4];
#pragma unroll
    for (int ff = 0; ff < 4; ++ff) {
      L0[ff] = left[f0 + ff];
      R0[ff] = right[f0 + ff];
      nv[ff] = nvalid[f0 + ff];
    }
    bool allfast = true;
#pragma unroll
    for (int ff = 0; ff < 4; ++ff) allfast &= (R0[ff] - L0[ff] == 8);
    if (allfast) {
      float qv[4], kv[4][8], vv[4][8];
      unsigned live[4];
#pragma unroll
      for (int ff = 0; ff < 4; ++ff) {
        qv[ff] = q[(size_t)(f0 + ff) * DMODEL + off];
        live[ff] = 0;
#pragma unroll
        for (int p = 0; p < 8; ++p) {
          kv[ff][p] = b2f(k[(size_t)(L0[ff] + p) * DMODEL + off]);
          vv[ff][p] = b2f(v[(size_t)(L0[ff] + p) * DMODEL + off]);
          live[ff] |= (ids[L0[ff] + p] != pad ? 1u : 0u) << p;
        }
      }
      float s[4][8];
#pragma unroll
      for (int ff = 0; ff < 4; ++ff)
#pragma unroll
        for (int p = 0; p < 8; ++p) s[ff][p] = qv[ff] * kv[ff][p];
#pragma unroll
      for (int m_ = 1; m_ < 64; m_ <<= 1)
#pragma unroll
        for (int ff = 0; ff < 4; ++ff)
#pragma unroll
          for (int p = 0; p < 8; ++p) s[ff][p] += __shfl_xor(s[ff][p], m_, 64);
#pragma unroll
      for (int ff = 0; ff < 4; ++ff) {
        if (nv[ff] == 0) continue;   // handled by the split-K/comb path
        float mx = -1e30f;
#pragma unroll
        for (int p = 0; p < 8; ++p) {
          s[ff][p] = ((live[ff] >> p) & 1u) ? s[ff][p] * 0.125f : -1e30f;
          mx = fmaxf(mx, s[ff][p]);
        }
        float l = 0.f, acc = 0.f;
#pragma unroll
        for (int p = 0; p < 8; ++p) {
          float w = __expf(s[ff][p] - mx);
          l += w;
          acc += w * vv[ff][p];
        }
        out[(size_t)(f0 + ff) * DMODEL + off] = bf16_1(acc / l);
      }
      return;
    }
    // slow path: per-feature serial online softmax (rare)
    for (int ff = 0; ff < 4; ++ff) {
      if (nv[ff] == 0) continue;
      const float qv = q[(size_t)(f0 + ff) * DMODEL + off];
      float m = -1e30f, l = 0.f, acc = 0.f;
      for (int p = L0[ff]; p < R0[ff]; ++p) {
        if (ids[p] == pad) continue;
        float s = allreduce64(qv * b2f(k[(size_t)p * DMODEL + off])) * 0.125f;
        float mn = fmaxf(m, s);
        float al = __expf(m - mn);
        float w = __expf(s - mn);
        l = l * al + w;
        acc = acc * al + w * b2f(v[(size_t)p * DMODEL + off]);
        m = mn;
      }
      out[(size_t)(f0 + ff) * DMODEL + off] = bf16_1(acc / l);
    }
    return;
  }

  // ---- fully-masked features: split-K pass 1, wave = (h, piece) ----
  const int nfull = *nfullp;
  if (nfull == 0) return;
  const int piece = x - nfx;
  const int pk = n / P;                    // keys per piece (multiple of 64)

  // per-wave q staging (wave-synchronous; no block barrier needed)
#pragma unroll
  for (int fl = 0; fl < 8; ++fl)
    q_lds[wid][fl * 64 + lane] =
        (fl < nfull) ? q[(size_t)fullist[fl] * DMODEL + h * 64 + lane] : 0.f;

  float m[8], l[8], acc[8];
#pragma unroll
  for (int f_ = 0; f_ < 8; ++f_) { m[f_] = -1e30f; l[f_] = 0.f; acc[f_] = 0.f; }

  for (int c = 0; c < pk; c += 64) {
    const int pc = piece * pk + c;
    float s[8];
#pragma unroll
    for (int f_ = 0; f_ < 8; ++f_) s[f_] = 0.f;
    const u16x8* kp = (const u16x8*)(k + (size_t)(pc + lane) * DMODEL + h * 64);
#pragma unroll 1
    for (int g = 0; g < 2; ++g) {
      u16x8 u0 = kp[g * 4 + 0], u1 = kp[g * 4 + 1], u2 = kp[g * 4 + 2],
            u3 = kp[g * 4 + 3];
      float4 kv0 = lo4(u0), kv1 = hi4(u0), kv2 = lo4(u1), kv3 = hi4(u1),
             kv4 = lo4(u2), kv5 = hi4(u2), kv6 = lo4(u3), kv7 = hi4(u3);
      const float4* qb = (const float4*)&q_lds[wid][g * 32];
#pragma unroll
      for (int f_ = 0; f_ < 8; ++f_) {
        float4 q0 = qb[f_ * 16 + 0], q1 = qb[f_ * 16 + 1], q2 = qb[f_ * 16 + 2],
               q3 = qb[f_ * 16 + 3], q4 = qb[f_ * 16 + 4], q5 = qb[f_ * 16 + 5],
               q6 = qb[f_ * 16 + 6], q7 = qb[f_ * 16 + 7];
        float acc0 = q0.x * kv0.x + q0.y * kv0.y + q0.z * kv0.z + q0.w * kv0.w;
        acc0 += q1.x * kv1.x + q1.y * kv1.y + q1.z * kv1.z + q1.w * kv1.w;
        acc0 += q2.x * kv2.x + q2.y * kv2.y + q2.z * kv2.z + q2.w * kv2.w;
        acc0 += q3.x * kv3.x + q3.y * kv3.y + q3.z * kv3.z + q3.w * kv3.w;
        acc0 += q4.x * kv4.x + q4.y * kv4.y + q4.z * kv4.z + q4.w * kv4.w;
        acc0 += q5.x * kv5.x + q5.y * kv5.y + q5.z * kv5.z + q5.w * kv5.w;
        acc0 += q6.x * kv6.x + q6.y * kv6.y + q6.z * kv6.z + q6.w * kv6.w;
        acc0 += q7.x * kv7.x + q7.y * kv7.y + q7.z * kv7.z + q7.w * kv7.w;
        s[f_] += acc0;
      }
    }
    float mx[8];
#pragma unroll
    for (int f_ = 0; f_ < 8; ++f_) mx[f_] = s[f_] * 0.125f;
#pragma unroll
    for (int f_ = 0; f_ < 8; ++f_) s[f_] = mx[f_];
#pragma unroll
    for (int st = 1; st < 64; st <<= 1)
#pragma unroll
      for (int f_ = 0; f_ < 8; ++f_) mx[f_] = fmaxf(mx[f_], __shfl_xor(mx[f_], st, 64));
    float alpha[8], w[8], sum[8];
#pragma unroll
    for (int f_ = 0; f_ < 8; ++f_) {
      float mn = fmaxf(m[f_], mx[f_]);
      alpha[f_] = __expf(m[f_] - mn);
      w[f_] = __expf(s[f_] - mn);
      m[f_] = mn;
      sum[f_] = w[f_];
    }
#pragma unroll
    for (int st = 1; st < 64; st <<= 1)
#pragma unroll
      for (int f_ = 0; f_ < 8; ++f_) sum[f_] += __shfl_xor(sum[f_], st, 64);
#pragma unroll
    for (int f_ = 0; f_ < 8; ++f_) l[f_] = l[f_] * alpha[f_] + sum[f_];
    *(float4*)&w_lds[wid][lane * 8]     = make_float4(w[0], w[1], w[2], w[3]);
    *(float4*)&w_lds[wid][lane * 8 + 4] = make_float4(w[4], w[5], w[6], w[7]);
#pragma unroll
    for (int f_ = 0; f_ < 8; ++f_) acc[f_] *= alpha[f_];
    const unsigned short* vb = v + (size_t)pc * DMODEL + h * 64 + lane;
#pragma unroll 4
    for (int kk = 0; kk < 64; ++kk) {
      float vd = b2f(vb[(size_t)kk * DMODEL]);
      float4 wa = *(const float4*)&w_lds[wid][kk * 8];
      float4 wb = *(const float4*)&w_lds[wid][kk * 8 + 4];
      acc[0] += wa.x * vd; acc[1] += wa.y * vd; acc[2] += wa.z * vd; acc[3] += wa.w * vd;
      acc[4] += wb.x * vd; acc[5] += wb.y * vd; acc[6] += wb.z * vd; acc[7] += wb.w * vd;
    }
  }

  for (int f_ = 0; f_ < nfull; ++f_) {
    size_t idx = ((size_t)f_ * NHEADS + h) * P + piece;
    if (lane == 0) { pm[idx] = m[f_]; pl[idx] = l[f_]; }
    pacc[idx * 64 + lane] = acc[f_];
  }
}

// Split-K pass 2: merge the P partials per (full-feature, head). Writes bf16.
__global__ __launch_bounds__(256) void attn_full_comb(
    const int* __restrict__ fullist, const int* __restrict__ nfullp,
    int P, const float* __restrict__ pm, const float* __restrict__ pl,
    const float* __restrict__ pacc, unsigned short* __restrict__ out) {
  const int fl = blockIdx.x, h = blockIdx.y;
  if (fl >= *nfullp) return;
  const int feat = fullist[fl];
  const int t = threadIdx.x, lane = t & 63, wv = t >> 6;
  const size_t base = ((size_t)fl * NHEADS + h) * P;

  __shared__ float s_pm[128];    // P <= 128
  __shared__ float s_sc[128];
  __shared__ float s_red[4];
  __shared__ float s_part[4][64];

  for (int sp = t; sp < P; sp += 256) s_pm[sp] = pm[base + sp];
  __syncthreads();
  float mloc = -1e30f;
  for (int sp = t; sp < P; sp += 256) mloc = fmaxf(mloc, s_pm[sp]);
#pragma unroll
  for (int st = 1; st < 64; st <<= 1) mloc = fmaxf(mloc, __shfl_xor(mloc, st, 64));
  if (lane == 0) s_red[wv] = mloc;
  __syncthreads();
  const float M = fmaxf(fmaxf(s_red[0], s_red[1]), fmaxf(s_red[2], s_red[3]));
  __syncthreads();
  float lloc = 0.f;
  for (int sp = t; sp < P; sp += 256) {
    float sc = __expf(s_pm[sp] - M);
    s_sc[sp] = sc;
    lloc += pl[base + sp] * sc;
  }
#pragma unroll
  for (int st = 1; st < 64; st <<= 1) lloc += __shfl_xor(lloc, st, 64);
  if (lane == 0) s_red[wv] = lloc;
  __syncthreads();
  const float Lt = s_red[0] + s_red[1] + s_red[2] + s_red[3];
  float At = 0.f;
  for (int sp = wv; sp < P; sp += 4)
    At += pacc[(base + sp) * 64 + lane] * s_sc[sp];
  s_part[wv][lane] = At;
  __syncthreads();
  if (wv == 0) {
    float tot = s_part[0][lane] + s_part[1][lane] + s_part[2][lane] + s_part[3][lane];
    out[(size_t)feat * DMODEL + h * 64 + lane] = bf16_1(tot / Lt);
  }
}

extern "C" void kernel_launch(void* const* d_in, const int* in_sizes, int n_in,
                              void* d_out, int out_size, void* d_ws, size_t ws_size,
                              hipStream_t stream) {
  const float* x_qk = (const float*)d_in[0];
  const float* x_v  = (const float*)d_in[1];
  const int* qm     = (const int*)d_in[2];
  const int* ids    = (const int*)d_in[3];
  const int* padp   = (const int*)d_in[4];
  const float* Wq = (const float*)d_in[5];
  const float* bq = (const float*)d_in[6];
  const float* Wk = (const float*)d_in[7];
  const float* bk = (const float*)d_in[8];
  const float* Wv = (const float*)d_in[9];
  const float* bv = (const float*)d_in[10];
  const float* Wo = (const float*)d_in[11];
  const float* bo = (const float*)d_in[12];

  const int n = in_sizes[0] / DMODEL;   // 8192
  const int f = out_size / DMODEL;      // 1024

  // ws: kfh,vfh bf16 | qf f32 | af bf16 | Wbf x4 | xqb,xvb bf16 | ints | partials
  unsigned short* kfh = (unsigned short*)d_ws;
  unsigned short* vfh = kfh + (size_t)n * DMODEL;
  float* qf = (float*)(vfh + (size_t)n * DMODEL);
  unsigned short* af = (unsigned short*)(qf + (size_t)f * DMODEL);
  unsigned short* wqb = af + (size_t)f * DMODEL;
  unsigned short* wkb = wqb + DMODEL * DMODEL;
  unsigned short* wvb = wkb + DMODEL * DMODEL;
  unsigned short* wob = wvb + DMODEL * DMODEL;
  unsigned short* xqb = wob + DMODEL * DMODEL;
  unsigned short* xvb = xqb + (size_t)n * DMODEL;
  int* left     = (int*)(xvb + (size_t)n * DMODEL);
  int* right    = left + f;
  int* nvalid   = right + f;
  int* fullrank = nvalid + f;
  int* fullist  = fullrank + f;
  int* nfull    = fullist + MAXFULL;
  size_t off_bytes = ((size_t)((char*)(nfull + 1) - (char*)d_ws) + 255) & ~(size_t)255;
  int P = 128;
  while (P > 16) {
    size_t need = (size_t)MAXFULL * NHEADS * P * 66 * sizeof(float);
    if (off_bytes + need <= ws_size && (n / P) % 64 == 0 && n % P == 0) break;
    P >>= 1;
  }
  float* pm = (float*)((char*)d_ws + off_bytes);
  float* pl = pm + (size_t)MAXFULL * NHEADS * P;
  float* pacc = pl + (size_t)MAXFULL * NHEADS * P;

  convAll<<<2049, 256, 0, stream>>>(Wq, Wk, Wv, Wo, (unsigned*)wqb,
                                    (unsigned*)wkb, (unsigned*)wvb,
                                    (unsigned*)wob, DMODEL * DMODEL,
                                    x_qk, x_v, (unsigned*)xqb, (unsigned*)xvb,
                                    n * DMODEL,
                                    qm, ids, padp, n, f, left, right, nvalid,
                                    fullrank, fullist, nfull);

  // main QKV GEMM at 256x256: K (96) | V (96) | Q-gather (12) = 204 blocks
  const int TKV256 = 3 * (n / 256);   // 96
  const int TF256  = 3 * (f / 256);   // 12
  GSeg g0 = { xqb, wkb, bk, nullptr, (void*)kfh, 0,           TKV256, 1 };
  GSeg g1 = { xvb, wvb, bv, nullptr, (void*)vfh, TKV256,      TKV256, 1 };
  GSeg g2 = { xqb, wqb, bq, left,    (void*)qf,  2 * TKV256,  TF256,  0 };
  gemm256<<<2 * TKV256 + TF256, 512, 0, stream>>>(g0, g1, g2);

  const int nfx = f / 4;              // 256 feature WGs (4 features per wave)
  attn_all<<<dim3(nfx + P, NHEADS / 4), 256, 0, stream>>>(qf, kfh, vfh, left,
                                                          right, nvalid, ids,
                                                          padp, af, fullist,
                                                          nfull, n, f, P, nfx,
                                                          pm, pl, pacc);
  attn_full_comb<<<dim3(MAXFULL, NHEADS), 256, 0, stream>>>(fullist, nfull, P,
                                                            pm, pl, pacc, af);

  gemmWo<<<(f / 64) * (DMODEL / 64), 64, 0, stream>>>(af, wob, bo, (float*)d_out);
}